// Round 9
// baseline (324.480 us; speedup 1.0000x reference)
//
#include <hip/hip_runtime.h>
#include <math.h>

// FCM mutual-kNN attention mixing. N=8192, D=256, K=16.
//   K1 prep:   feats->bf16, row sqnorms, zero cnt_g
//   K1b stats: deterministic reduction of sq -> mu/var
//   K2 gemm:   A panel (64 rows) resident in LDS, B streamed global->regs,
//              NO barriers in main loop; fused threshold select -> packed
//              (keyq<<13)|idx into LDS cbuf -> one merge/block. 2 blocks/CU.
//   K2b fallback: detect + full-rescan repair of bad rows (expected none)
//   K3 refine: top-24 by packed key (in-reg) -> fp64 exact d2+dot -> top-17
//   K4 out:    mutual mask + sparse softmax + mix + normalize
#define NPTS 8192
#define DIM  256
#define NSLOT 17
#define CAP  256
#define LCAP 48
#define RSEL 24
#define ZTH  (-2.45f)
typedef unsigned int uint;
typedef unsigned short ushort;
typedef __attribute__((ext_vector_type(8))) short bf16x8;
typedef __attribute__((ext_vector_type(4))) float f32x4;

__device__ __forceinline__ ushort f2bf(float f) {
    uint x = __float_as_uint(f);
    return (ushort)((x + 0x7fffu + ((x >> 16) & 1u)) >> 16);
}

// ---------------- K1: bf16 copy + sqnorms + cnt_g=0 ----------------
__global__ void prep_kernel(const float* __restrict__ feats, ushort* __restrict__ fb,
                            float* __restrict__ sq, int* __restrict__ cnt_g) {
    const int row  = blockIdx.x * 4 + (threadIdx.x >> 6);
    const int lane = threadIdx.x & 63;
    const float4 v = *reinterpret_cast<const float4*>(feats + (size_t)row * DIM + lane * 4);
    ushort4 b; b.x = f2bf(v.x); b.y = f2bf(v.y); b.z = f2bf(v.z); b.w = f2bf(v.w);
    *reinterpret_cast<ushort4*>(fb + (size_t)row * DIM + lane * 4) = b;
    float p = v.x * v.x + v.y * v.y + v.z * v.z + v.w * v.w;
#pragma unroll
    for (int off = 32; off > 0; off >>= 1) p += __shfl_down(p, off, 64);
    if (lane == 0) { sq[row] = p; cnt_g[row] = 0; }
}

// ---------------- K1b: deterministic stats (mu, var) ----------------
__global__ void stats_kernel(const float* __restrict__ sq, float* __restrict__ musig) {
    __shared__ double s0s[16], s1s[16];
    const int t = threadIdx.x, lane = t & 63, w = t >> 6;
    double s0 = 0.0, s1 = 0.0;
    for (int r = t; r < NPTS; r += 1024) {
        const double v = (double)sq[r];
        s0 += v; s1 += v * v;
    }
#pragma unroll
    for (int off = 32; off > 0; off >>= 1) {
        s0 += __shfl_down(s0, off, 64);
        s1 += __shfl_down(s1, off, 64);
    }
    if (lane == 0) { s0s[w] = s0; s1s[w] = s1; }
    __syncthreads();
    if (t == 0) {
        double a0 = 0.0, a1 = 0.0;
#pragma unroll
        for (int q = 0; q < 16; ++q) { a0 += s0s[q]; a1 += s1s[q]; }
        const double mu = a0 / NPTS;
        const double var = a1 / NPTS - mu * mu;
        musig[0] = (float)mu;
        musig[1] = (float)fmax(var, 1.0);
    }
}

// ---------------- K2: barrier-free MFMA GEMM + fused threshold select ----------------
// 512 thr = 8 waves, 2 blocks/CU (~46 KB LDS). Block: 64 rows x 2048-col quarter.
// Wave w owns cols w*32..w*32+31 of each 256-col tile (disjoint -> B in regs).
// A panel staged once in LDS (XOR-swizzled), read-only afterwards.
__global__ __launch_bounds__(512, 4) void gemm_select_kernel(
    const ushort* __restrict__ fb, const float* __restrict__ sq,
    const float* __restrict__ musig, int* __restrict__ cand, int* __restrict__ cnt_g) {
    __shared__ ushort As[64 * 256];      // 32 KB [row][k], byte ^= (row&7)<<4
    __shared__ int    cbuf[64][LCAP];    // 12 KB packed (keyq<<13)|idx
    __shared__ float  Ts[64], sqi_s[64];
    __shared__ int    cnt[64];
    __shared__ int    base_s[64], n_s[64];

    const int tid = threadIdx.x;
    const int w   = tid >> 6;
    const int l   = tid & 63;
    const int l15 = l & 15, lg = l >> 4;
    const int rowblk = (blockIdx.x >> 3) * 2 + (blockIdx.x & 1);
    const int row0   = rowblk * 64;
    const int Jbase  = ((blockIdx.x & 7) >> 1) * 2048;   // quarter pinned per XCD

    if (tid < 64) {
        const float mu  = musig[0];
        const float var = musig[1];
        const float qi  = sq[row0 + tid];
        sqi_s[tid] = qi;
        Ts[tid]    = qi + mu + ZTH * sqrtf(var + 4.f * qi);
        cnt[tid]   = 0;
    }
    {   // stage A panel once: 64 rows x 256 k
        const int row = tid >> 3, kq = tid & 7;
        const ushort* src = fb + (size_t)(row0 + row) * DIM;
        char* dst = reinterpret_cast<char*>(As);
        const int sw = (row & 7) << 4;
#pragma unroll
        for (int p = 0; p < 4; ++p) {
            const bf16x8 v = *reinterpret_cast<const bf16x8*>(src + (kq + p * 8) * 8);
            *reinterpret_cast<bf16x8*>(dst + ((row * 512 + (kq + p * 8) * 16) ^ sw)) = v;
        }
    }
    __syncthreads();                     // the ONLY barrier before the merge

    const int gcol = w * 32;
    const ushort* colp = fb + (size_t)(Jbase + gcol + l15) * DIM + lg * 8;

    bf16x8 bb[2][2];
#pragma unroll
    for (int cf = 0; cf < 2; ++cf)
        bb[0][cf] = *reinterpret_cast<const bf16x8*>(colp + cf * 16 * DIM);

    for (int tile = 0; tile < 8; ++tile) {
        f32x4 acc[4][2];
#pragma unroll
        for (int mf = 0; mf < 4; ++mf) {
            acc[mf][0] = (f32x4){0.f, 0.f, 0.f, 0.f};
            acc[mf][1] = (f32x4){0.f, 0.f, 0.f, 0.f};
        }
#pragma unroll
        for (int ks = 0; ks < 8; ++ks) {
            const int cur = ks & 1;
            // prefetch next 32-k step (register ping-pong, no LDS, no barrier)
            if (tile < 7 || ks < 7) {
                const int ntile = (ks == 7) ? tile + 1 : tile;
                const int nks   = (ks == 7) ? 0 : ks + 1;
#pragma unroll
                for (int cf = 0; cf < 2; ++cf)
                    bb[cur ^ 1][cf] = *reinterpret_cast<const bf16x8*>(
                        colp + (ntile * 256 + cf * 16) * DIM + nks * 32);
            }
            bf16x8 af[4];
#pragma unroll
            for (int mf = 0; mf < 4; ++mf) {
                const int row = mf * 16 + l15;
                af[mf] = *reinterpret_cast<const bf16x8*>(
                    reinterpret_cast<const char*>(As) +
                    ((row * 512 + ks * 64 + lg * 16) ^ ((row & 7) << 4)));
            }
#pragma unroll
            for (int mf = 0; mf < 4; ++mf) {
                acc[mf][0] = __builtin_amdgcn_mfma_f32_16x16x32_bf16(af[mf], bb[cur][0], acc[mf][0], 0, 0, 0);
                acc[mf][1] = __builtin_amdgcn_mfma_f32_16x16x32_bf16(af[mf], bb[cur][1], acc[mf][1], 0, 0, 0);
            }
        }
        // ---- per-tile epilogue: threshold select, packed into LDS cbuf ----
        const int Jt = Jbase + tile * 256;
        float sqc[2];
#pragma unroll
        for (int cf = 0; cf < 2; ++cf) sqc[cf] = sq[Jt + gcol + cf * 16 + l15];
#pragma unroll
        for (int mf = 0; mf < 2 * 2; ++mf) {}
#pragma unroll
        for (int mf = 0; mf < 4; ++mf)
#pragma unroll
            for (int cf = 0; cf < 2; ++cf)
#pragma unroll
                for (int r = 0; r < 4; ++r) {
                    const int row = mf * 16 + lg * 4 + r;
                    const float tt = Ts[row];
                    const float key = sqi_s[row] + sqc[cf] - 2.f * acc[mf][cf][r];
                    if (key < tt) {
                        const int kq2 = min((int)((tt - key) * 4096.f), 524287);
                        const uint val = ((uint)max(kq2, 0) << 13) |
                                         (uint)(Jt + gcol + cf * 16 + l15);
                        const int pos = atomicAdd(&cnt[row], 1);
                        if (pos < LCAP) cbuf[row][pos] = (int)val;
                    }
                }
    }
    __syncthreads();
    if (tid < 64) {
        const int local = cnt[tid];
        const int n = min(local, LCAP);
        const int add = (local > LCAP) ? (n + (1 << 20)) : n;   // poison on overflow
        base_s[tid] = atomicAdd(&cnt_g[row0 + tid], add);
        n_s[tid] = n;
    }
    __syncthreads();
    for (int s = tid; s < 64 * LCAP; s += 512) {
        const int r = s / LCAP, k2 = s - r * LCAP;
        if (k2 < n_s[r]) {
            const int b = base_s[r] + k2;
            if (b < CAP) cand[(size_t)(row0 + r) * CAP + b] = cbuf[r][k2];
        }
    }
}

// ---------------- K2b: detect + repair bad rows (expected none) ----------------
__global__ void fallback_kernel(const float* __restrict__ feats, const float* __restrict__ sq,
                                int* __restrict__ cand, int* __restrict__ cnt_g) {
    __shared__ float fi_s[DIM];
    __shared__ float keys[NPTS];
    __shared__ float rkey[4];
    __shared__ int   rid[4];
    const int t = threadIdx.x;
    for (int row = blockIdx.x; row < NPTS; row += gridDim.x) {
        const int v = cnt_g[row];
        if (v >= NSLOT && v <= CAP) continue;
        fi_s[t] = feats[(size_t)row * DIM + t];
        __syncthreads();
        const float sqi = sq[row];
        for (int p = 0; p < NPTS / 256; ++p) {
            const int jj = p * 256 + t;
            const float* fj = feats + (size_t)jj * DIM;
            float d = 0.f;
            for (int dq = 0; dq < DIM / 4; ++dq) {
                const float4 b4 = *reinterpret_cast<const float4*>(fj + dq * 4);
                const float4 a4 = *reinterpret_cast<const float4*>(&fi_s[dq * 4]);
                d = fmaf(a4.x, b4.x, fmaf(a4.y, b4.y, fmaf(a4.z, b4.z, fmaf(a4.w, b4.w, d))));
            }
            keys[jj] = sqi + sq[jj] - 2.f * d;
        }
        __syncthreads();
        for (int r = 0; r < 64; ++r) {
            float bk = INFINITY; int bj = 0x7fffffff;
            for (int p = 0; p < NPTS / 256; ++p) {
                const int jj = p * 256 + t;
                const float kv = keys[jj];
                if (kv < bk || (kv == bk && jj < bj)) { bk = kv; bj = jj; }
            }
#pragma unroll
            for (int off = 1; off <= 32; off <<= 1) {
                const float ok = __shfl_xor(bk, off, 64);
                const int   oj = __shfl_xor(bj, off, 64);
                if (ok < bk || (ok == bk && oj < bj)) { bk = ok; bj = oj; }
            }
            if ((t & 63) == 0) { rkey[t >> 6] = bk; rid[t >> 6] = bj; }
            __syncthreads();
            float fk = rkey[0]; int fj2 = rid[0];
#pragma unroll
            for (int q = 1; q < 4; ++q)
                if (rkey[q] < fk || (rkey[q] == fk && rid[q] < fj2)) { fk = rkey[q]; fj2 = rid[q]; }
            if (t == 0) {   // packed: rank-ordered key so refine's top-24 keeps rank order
                cand[(size_t)row * CAP + r] = (int)(((uint)(524287 - r) << 13) | (uint)fj2);
                keys[fj2] = INFINITY;
            }
            __syncthreads();
        }
        if (t == 0) cnt_g[row] = 64;
        __syncthreads();
    }
}

// ---------------- K3: top-24 by packed key, then fp64 refine -> exact top-17 ----------------
__global__ __launch_bounds__(256) void refine_kernel(
    const float* __restrict__ feats, const int* __restrict__ cand,
    const int* __restrict__ cnt_g, int* __restrict__ fidx, float* __restrict__ fscr) {
    __shared__ float  fi_s[DIM];
    __shared__ int    sel[RSEL];
    __shared__ double kdd[RSEL];
    __shared__ float  kdot[RSEL];
    __shared__ int    kidx[RSEL];
    const int t = threadIdx.x, i = blockIdx.x;
    fi_s[t] = feats[(size_t)i * DIM + t];
    const int nc = min(cnt_g[i], CAP);
    const int nsel = min(nc, RSEL);
    __syncthreads();
    if (t < 64) {                        // wave 0: top-nsel by packed composite
        const int* crow = cand + (size_t)i * CAP;
        uint pk[4];
#pragma unroll
        for (int p = 0; p < 4; ++p) {
            const int idx4 = p * 64 + t;
            pk[p] = (idx4 < nc) ? (uint)crow[idx4] : 0u;
        }
        for (int r = 0; r < nsel; ++r) {
            uint best = max(max(pk[0], pk[1]), max(pk[2], pk[3]));
#pragma unroll
            for (int off = 1; off <= 32; off <<= 1)
                best = max(best, (uint)__shfl_xor((int)best, off, 64));
            if (t == 0) sel[r] = (int)best;
#pragma unroll
            for (int p = 0; p < 4; ++p) if (pk[p] == best) pk[p] = 0u;
        }
    }
    __syncthreads();
    const int c = t >> 3, ch = t & 7;    // 8 lanes per candidate, 32 dims each
    if (c < nsel) {
        const int j = sel[c] & 8191;
        const float* fj = feats + (size_t)j * DIM + ch * 32;
        const float* fi = fi_s + ch * 32;
        double dd = 0.0, dot = 0.0;
#pragma unroll
        for (int q = 0; q < 8; ++q) {
            const float4 a4 = *reinterpret_cast<const float4*>(fi + q * 4);
            const float4 b4 = *reinterpret_cast<const float4*>(fj + q * 4);
            const double dx = (double)a4.x - b4.x, dy = (double)a4.y - b4.y;
            const double dz = (double)a4.z - b4.z, dw = (double)a4.w - b4.w;
            dd  += dx * dx + dy * dy + dz * dz + dw * dw;
            dot += (double)a4.x * b4.x + (double)a4.y * b4.y +
                   (double)a4.z * b4.z + (double)a4.w * b4.w;
        }
        dd  += __shfl_xor(dd, 1, 64);  dd  += __shfl_xor(dd, 2, 64);  dd  += __shfl_xor(dd, 4, 64);
        dot += __shfl_xor(dot, 1, 64); dot += __shfl_xor(dot, 2, 64); dot += __shfl_xor(dot, 4, 64);
        if (ch == 0) { kdd[c] = dd; kidx[c] = j; kdot[c] = (float)dot; }
    }
    __syncthreads();
    if (t < 64) {                        // wave 0: exact top-17 by (d2, idx)
        double kk = (t < nsel) ? kdd[t] : 1e300;
        int    jj = (t < nsel) ? kidx[t] : 0x7fffffff;
        float  ss = (t < nsel) ? kdot[t] : 0.f;
        for (int r = 0; r < NSLOT; ++r) {
            double bk = kk; int bj = jj; float bs = ss;
#pragma unroll
            for (int off = 1; off <= 32; off <<= 1) {
                const double ok = __shfl_xor(bk, off, 64);
                const int    oj = __shfl_xor(bj, off, 64);
                const float  os = __shfl_xor(bs, off, 64);
                if (ok < bk || (ok == bk && oj < bj)) { bk = ok; bj = oj; bs = os; }
            }
            if (t == 0) { fidx[(size_t)i * NSLOT + r] = bj; fscr[(size_t)i * NSLOT + r] = bs; }
            if (jj == bj) kk = 1e300;
        }
    }
}

// ---------------- K4: mutual mask + sparse softmax + mix + normalize ----------------
__global__ void fcm_out_kernel(const float* __restrict__ feats,
                               const int* __restrict__ knn_idx,
                               const float* __restrict__ knn_scr,
                               float* __restrict__ out) {
    const int w    = threadIdx.x >> 6;
    const int lane = threadIdx.x & 63;
    const int i    = blockIdx.x * 4 + w;

    int jt = -1; float st = 0.f; bool valid = false;
    if (lane < NSLOT) {
        jt = knn_idx[(size_t)i * NSLOT + lane];
        st = knn_scr[(size_t)i * NSLOT + lane];
        if (jt != i) {
            const int* nb = knn_idx + (size_t)jt * NSLOT;
#pragma unroll
            for (int s = 0; s < NSLOT; ++s) valid |= (nb[s] == i);
        }
    }
    float val = valid ? st : -INFINITY;
#pragma unroll
    for (int off = 32; off > 0; off >>= 1) val = fmaxf(val, __shfl_xor(val, off, 64));
    const float m  = fmaxf(1.0f, val);
    const float wt = valid ? expf(st - m) : 0.f;
    float ws = wt;
#pragma unroll
    for (int off = 32; off > 0; off >>= 1) ws += __shfl_xor(ws, off, 64);
    const float wdiag = expf(1.0f - m);
    const float inv   = 1.0f / (ws + wdiag);

    const float4 fi = *reinterpret_cast<const float4*>(feats + (size_t)i * DIM + lane * 4);
    float ax = fi.x * wdiag, ay = fi.y * wdiag, az = fi.z * wdiag, aw = fi.w * wdiag;
    for (int t = 0; t < NSLOT; ++t) {
        const float wtt = __shfl(wt, t, 64);
        const int   jj  = __shfl(jt, t, 64);
        if (wtt > 0.f) {
            const float4 fj = *reinterpret_cast<const float4*>(feats + (size_t)jj * DIM + lane * 4);
            ax = fmaf(wtt, fj.x, ax); ay = fmaf(wtt, fj.y, ay);
            az = fmaf(wtt, fj.z, az); aw = fmaf(wtt, fj.w, aw);
        }
    }
    const float ox = fmaf(ax, inv, fi.x), oy = fmaf(ay, inv, fi.y);
    const float oz = fmaf(az, inv, fi.z), ow = fmaf(aw, inv, fi.w);
    float nn = ox * ox + oy * oy + oz * oz + ow * ow;
#pragma unroll
    for (int off = 32; off > 0; off >>= 1) nn += __shfl_xor(nn, off, 64);
    const float scl = 1.0f / fmaxf(sqrtf(nn), 1e-12f);
    float4 o; o.x = ox * scl; o.y = oy * scl; o.z = oz * scl; o.w = ow * scl;
    *reinterpret_cast<float4*>(out + (size_t)i * DIM + lane * 4) = o;
}

extern "C" void kernel_launch(void* const* d_in, const int* in_sizes, int n_in,
                              void* d_out, int out_size, void* d_ws, size_t ws_size,
                              hipStream_t stream) {
    (void)in_sizes; (void)n_in; (void)out_size; (void)ws_size;
    const float* feats = (const float*)d_in[0];
    float* out = (float*)d_out;
    char* ws = (char*)d_ws;
    size_t off = 0;
    float*  sq    = (float*) (ws + off); off += NPTS * 4;                 // 32 KB
    float*  musig = (float*) (ws + off); off += 128;
    ushort* fb    = (ushort*)(ws + off); off += (size_t)NPTS * DIM * 2;   // 4 MB
    int*    cand  = (int*)   (ws + off); off += (size_t)NPTS * CAP * 4;   // 8 MB
    int*    cnt_g = (int*)   (ws + off); off += NPTS * 4;
    int*    fidx  = (int*)   (ws + off); off += NPTS * NSLOT * 4;
    float*  fscr  = (float*) (ws + off); off += NPTS * NSLOT * 4;

    prep_kernel<<<NPTS / 4, 256, 0, stream>>>(feats, fb, sq, cnt_g);
    stats_kernel<<<1, 1024, 0, stream>>>(sq, musig);
    gemm_select_kernel<<<(NPTS / 64) * 4, 512, 0, stream>>>(fb, sq, musig, cand, cnt_g);
    fallback_kernel<<<64, 256, 0, stream>>>(feats, sq, cand, cnt_g);
    refine_kernel<<<NPTS, 256, 0, stream>>>(feats, cand, cnt_g, fidx, fscr);
    fcm_out_kernel<<<NPTS / 4, 256, 0, stream>>>(feats, fidx, fscr, out);
}

// Round 10
// 219.930 us; speedup vs baseline: 1.4754x; 1.4754x over previous
//
#include <hip/hip_runtime.h>
#include <math.h>

// FCM mutual-kNN attention mixing. N=8192, D=256, K=16.
//   K1 prep:   feats->bf16, row sqnorms, zero cnt_g
//   K1b stats: deterministic reduction of sq -> mu/var
//   K2 gemm:   bf16 MFMA F F^T, 64 rows x 2048-col quarter, dbuf LDS staging,
//              fused threshold select -> packed (keyq<<13)|idx LDS cbuf ->
//              one merge/block. launch_bounds(512,2): 128 VGPR, NO spills.
//   K2b fallback: detect + full-rescan repair of bad rows (expected none)
//   K3 refine: top-24 by packed key (in-reg) -> fp64 exact d2+dot -> top-17
//   K4 out:    mutual mask + sparse softmax + mix + normalize
#define NPTS 8192
#define DIM  256
#define NSLOT 17
#define CAP  256
#define LCAP 48
#define RSEL 24
#define ZTH  (-2.45f)
typedef unsigned int uint;
typedef unsigned short ushort;
typedef __attribute__((ext_vector_type(8))) short bf16x8;
typedef __attribute__((ext_vector_type(4))) float f32x4;

__device__ __forceinline__ ushort f2bf(float f) {
    uint x = __float_as_uint(f);
    return (ushort)((x + 0x7fffu + ((x >> 16) & 1u)) >> 16);
}

// ---------------- K1: bf16 copy + sqnorms + cnt_g=0 ----------------
__global__ void prep_kernel(const float* __restrict__ feats, ushort* __restrict__ fb,
                            float* __restrict__ sq, int* __restrict__ cnt_g) {
    const int row  = blockIdx.x * 4 + (threadIdx.x >> 6);
    const int lane = threadIdx.x & 63;
    const float4 v = *reinterpret_cast<const float4*>(feats + (size_t)row * DIM + lane * 4);
    ushort4 b; b.x = f2bf(v.x); b.y = f2bf(v.y); b.z = f2bf(v.z); b.w = f2bf(v.w);
    *reinterpret_cast<ushort4*>(fb + (size_t)row * DIM + lane * 4) = b;
    float p = v.x * v.x + v.y * v.y + v.z * v.z + v.w * v.w;
#pragma unroll
    for (int off = 32; off > 0; off >>= 1) p += __shfl_down(p, off, 64);
    if (lane == 0) { sq[row] = p; cnt_g[row] = 0; }
}

// ---------------- K1b: deterministic stats (mu, var) ----------------
__global__ void stats_kernel(const float* __restrict__ sq, float* __restrict__ musig) {
    __shared__ double s0s[16], s1s[16];
    const int t = threadIdx.x, lane = t & 63, w = t >> 6;
    double s0 = 0.0, s1 = 0.0;
    for (int r = t; r < NPTS; r += 1024) {
        const double v = (double)sq[r];
        s0 += v; s1 += v * v;
    }
#pragma unroll
    for (int off = 32; off > 0; off >>= 1) {
        s0 += __shfl_down(s0, off, 64);
        s1 += __shfl_down(s1, off, 64);
    }
    if (lane == 0) { s0s[w] = s0; s1s[w] = s1; }
    __syncthreads();
    if (t == 0) {
        double a0 = 0.0, a1 = 0.0;
#pragma unroll
        for (int q = 0; q < 16; ++q) { a0 += s0s[q]; a1 += s1s[q]; }
        const double mu = a0 / NPTS;
        const double var = a1 / NPTS - mu * mu;
        musig[0] = (float)mu;
        musig[1] = (float)fmax(var, 1.0);
    }
}

// ---------------- K2: MFMA GEMM + fused threshold select ----------------
// 512 thr = 8 waves, 2 blocks/CU (77.3 KB LDS, 128 VGPR budget).
// Block: 64 rows x 2048-col quarter; quarter pinned per XCD via bid&7.
// Wave: row-half h=w>>2 (32 rows), col-group g=w&3 (64 cols).
__global__ __launch_bounds__(512, 2) void gemm_select_kernel(
    const ushort* __restrict__ fb, const float* __restrict__ sq,
    const float* __restrict__ musig, int* __restrict__ cand, int* __restrict__ cnt_g) {
    __shared__ ushort Bs[2][256 * 64];   // 64 KB, [buf][col][k] swizzled
    __shared__ int    cbuf[64][LCAP];    // 12 KB packed (keyq<<13)|idx
    __shared__ float  Ts[64], sqi_s[64];
    __shared__ int    cnt[64];
    __shared__ int    base_s[64], n_s[64];

    const int tid = threadIdx.x;
    const int w   = tid >> 6;
    const int l   = tid & 63;
    const int l15 = l & 15, lg = l >> 4;
    const int h   = w >> 2;
    const int g   = w & 3;
    const int rowblk = (blockIdx.x >> 3) * 2 + (blockIdx.x & 1);
    const int row0   = rowblk * 64;
    const int Jbase  = ((blockIdx.x & 7) >> 1) * 2048;

    if (tid < 64) {
        const float mu  = musig[0];
        const float var = musig[1];
        const float qi  = sq[row0 + tid];
        sqi_s[tid] = qi;
        Ts[tid]    = qi + mu + ZTH * sqrtf(var + 4.f * qi);
        cnt[tid]   = 0;
    }

    // A resident: a[mf][ks] = F[row0 + h*32 + mf*16 + l15][ks*32 + lg*8 .. +7]
    bf16x8 a[2][8];
#pragma unroll
    for (int mf = 0; mf < 2; ++mf) {
        const ushort* ap = fb + (size_t)(row0 + h * 32 + mf * 16 + l15) * DIM + lg * 8;
#pragma unroll
        for (int ks = 0; ks < 8; ++ks)
            a[mf][ks] = *reinterpret_cast<const bf16x8*>(ap + ks * 32);
    }

    {   // prologue: stage chunk 0 into Bs[0]
        const int kslot = tid & 7;
#pragma unroll
        for (int p = 0; p < 4; ++p) {
            const int col = (tid >> 3) + p * 64;
            const bf16x8 v = *reinterpret_cast<const bf16x8*>(
                fb + (size_t)(Jbase + col) * DIM + kslot * 8);
            const int byt = col * 128 + ((kslot * 16) ^ ((col & 7) << 4));
            *reinterpret_cast<bf16x8*>(reinterpret_cast<char*>(Bs[0]) + byt) = v;
        }
    }

    f32x4 acc[2][4];
#pragma unroll
    for (int mf = 0; mf < 2; ++mf)
#pragma unroll
        for (int cf = 0; cf < 4; ++cf) acc[mf][cf] = (f32x4){0.f, 0.f, 0.f, 0.f};

    for (int tile = 0; tile < 8; ++tile) {
#pragma unroll
        for (int kc4 = 0; kc4 < 4; ++kc4) {
            __syncthreads();             // Bs[kc4&1] staged; other buffer free
            bf16x8 st[4];
            const int cnext = tile * 4 + kc4 + 1;
            const bool do_stage = (cnext < 32);
            if (do_stage) {
                const int Jn  = Jbase + (cnext >> 2) * 256;
                const int kcn = ((kc4 + 1) & 3) * 64;
                const int kslot = tid & 7;
#pragma unroll
                for (int p = 0; p < 4; ++p) {
                    const int col = (tid >> 3) + p * 64;
                    st[p] = *reinterpret_cast<const bf16x8*>(
                        fb + (size_t)(Jn + col) * DIM + kcn + kslot * 8);
                }
            }
            {   // compute chunk from Bs[kc4&1]
                const char* Bb = reinterpret_cast<const char*>(Bs[kc4 & 1]);
#pragma unroll
                for (int kk = 0; kk < 2; ++kk) {
                    bf16x8 b[4];
#pragma unroll
                    for (int cf = 0; cf < 4; ++cf) {
                        const int col = g * 64 + cf * 16 + l15;
                        b[cf] = *reinterpret_cast<const bf16x8*>(
                            Bb + col * 128 + ((kk * 64 + lg * 16) ^ ((col & 7) << 4)));
                    }
#pragma unroll
                    for (int mf = 0; mf < 2; ++mf)
#pragma unroll
                        for (int cf = 0; cf < 4; ++cf)
                            acc[mf][cf] = __builtin_amdgcn_mfma_f32_16x16x32_bf16(
                                a[mf][kc4 * 2 + kk], b[cf], acc[mf][cf], 0, 0, 0);
                }
            }
            if (do_stage) {
                const int kslot = tid & 7;
                char* Bn = reinterpret_cast<char*>(Bs[(kc4 + 1) & 1]);
#pragma unroll
                for (int p = 0; p < 4; ++p) {
                    const int col = (tid >> 3) + p * 64;
                    const int byt = col * 128 + ((kslot * 16) ^ ((col & 7) << 4));
                    *reinterpret_cast<bf16x8*>(Bn + byt) = st[p];
                }
            }
        }
        // ---- per-tile epilogue: threshold select, packed into LDS cbuf ----
        const int Jt = Jbase + tile * 256;
        float sqc[4];
#pragma unroll
        for (int cf = 0; cf < 4; ++cf) sqc[cf] = sq[Jt + g * 64 + cf * 16 + l15];
#pragma unroll
        for (int mf = 0; mf < 2; ++mf)
#pragma unroll
            for (int cf = 0; cf < 4; ++cf)
#pragma unroll
                for (int r = 0; r < 4; ++r) {
                    const int row = h * 32 + mf * 16 + lg * 4 + r;
                    const float tt = Ts[row];
                    const float key = sqi_s[row] + sqc[cf] - 2.f * acc[mf][cf][r];
                    if (key < tt) {
                        const int kq2 = min((int)((tt - key) * 4096.f), 524287);
                        const uint val = ((uint)max(kq2, 0) << 13) |
                                         (uint)(Jt + g * 64 + cf * 16 + l15);
                        const int pos = atomicAdd(&cnt[row], 1);
                        if (pos < LCAP) cbuf[row][pos] = (int)val;
                    }
                }
#pragma unroll
        for (int mf = 0; mf < 2; ++mf)
#pragma unroll
            for (int cf = 0; cf < 4; ++cf) acc[mf][cf] = (f32x4){0.f, 0.f, 0.f, 0.f};
    }
    __syncthreads();
    if (tid < 64) {
        const int local = cnt[tid];
        const int n = min(local, LCAP);
        const int add = (local > LCAP) ? (n + (1 << 20)) : n;   // poison on overflow
        base_s[tid] = atomicAdd(&cnt_g[row0 + tid], add);
        n_s[tid] = n;
    }
    __syncthreads();
    for (int s = tid; s < 64 * LCAP; s += 512) {
        const int r = s / LCAP, k2 = s - r * LCAP;
        if (k2 < n_s[r]) {
            const int b = base_s[r] + k2;
            if (b < CAP) cand[(size_t)(row0 + r) * CAP + b] = cbuf[r][k2];
        }
    }
}

// ---------------- K2b: detect + repair bad rows (expected none) ----------------
__global__ void fallback_kernel(const float* __restrict__ feats, const float* __restrict__ sq,
                                int* __restrict__ cand, int* __restrict__ cnt_g) {
    __shared__ float fi_s[DIM];
    __shared__ float keys[NPTS];
    __shared__ float rkey[4];
    __shared__ int   rid[4];
    const int t = threadIdx.x;
    for (int row = blockIdx.x; row < NPTS; row += gridDim.x) {
        const int v = cnt_g[row];
        if (v >= NSLOT && v <= CAP) continue;
        fi_s[t] = feats[(size_t)row * DIM + t];
        __syncthreads();
        const float sqi = sq[row];
        for (int p = 0; p < NPTS / 256; ++p) {
            const int jj = p * 256 + t;
            const float* fj = feats + (size_t)jj * DIM;
            float d = 0.f;
            for (int dq = 0; dq < DIM / 4; ++dq) {
                const float4 b4 = *reinterpret_cast<const float4*>(fj + dq * 4);
                const float4 a4 = *reinterpret_cast<const float4*>(&fi_s[dq * 4]);
                d = fmaf(a4.x, b4.x, fmaf(a4.y, b4.y, fmaf(a4.z, b4.z, fmaf(a4.w, b4.w, d))));
            }
            keys[jj] = sqi + sq[jj] - 2.f * d;
        }
        __syncthreads();
        for (int r = 0; r < 64; ++r) {
            float bk = INFINITY; int bj = 0x7fffffff;
            for (int p = 0; p < NPTS / 256; ++p) {
                const int jj = p * 256 + t;
                const float kv = keys[jj];
                if (kv < bk || (kv == bk && jj < bj)) { bk = kv; bj = jj; }
            }
#pragma unroll
            for (int off = 1; off <= 32; off <<= 1) {
                const float ok = __shfl_xor(bk, off, 64);
                const int   oj = __shfl_xor(bj, off, 64);
                if (ok < bk || (ok == bk && oj < bj)) { bk = ok; bj = oj; }
            }
            if ((t & 63) == 0) { rkey[t >> 6] = bk; rid[t >> 6] = bj; }
            __syncthreads();
            float fk = rkey[0]; int fj2 = rid[0];
#pragma unroll
            for (int q = 1; q < 4; ++q)
                if (rkey[q] < fk || (rkey[q] == fk && rid[q] < fj2)) { fk = rkey[q]; fj2 = rid[q]; }
            if (t == 0) {   // rank-ordered packed key so refine's top-24 keeps rank order
                cand[(size_t)row * CAP + r] = (int)(((uint)(524287 - r) << 13) | (uint)fj2);
                keys[fj2] = INFINITY;
            }
            __syncthreads();
        }
        if (t == 0) cnt_g[row] = 64;
        __syncthreads();
    }
}

// ---------------- K3: top-24 by packed key, then fp64 refine -> exact top-17 ----------------
__global__ __launch_bounds__(256) void refine_kernel(
    const float* __restrict__ feats, const int* __restrict__ cand,
    const int* __restrict__ cnt_g, int* __restrict__ fidx, float* __restrict__ fscr) {
    __shared__ float  fi_s[DIM];
    __shared__ int    sel[RSEL];
    __shared__ double kdd[RSEL];
    __shared__ float  kdot[RSEL];
    __shared__ int    kidx[RSEL];
    const int t = threadIdx.x, i = blockIdx.x;
    fi_s[t] = feats[(size_t)i * DIM + t];
    const int nc = min(cnt_g[i], CAP);
    const int nsel = min(nc, RSEL);
    __syncthreads();
    if (t < 64) {                        // wave 0: top-nsel by packed composite
        const int* crow = cand + (size_t)i * CAP;
        uint pk[4];
#pragma unroll
        for (int p = 0; p < 4; ++p) {
            const int idx4 = p * 64 + t;
            pk[p] = (idx4 < nc) ? (uint)crow[idx4] : 0u;
        }
        for (int r = 0; r < nsel; ++r) {
            uint best = max(max(pk[0], pk[1]), max(pk[2], pk[3]));
#pragma unroll
            for (int off = 1; off <= 32; off <<= 1)
                best = max(best, (uint)__shfl_xor((int)best, off, 64));
            if (t == 0) sel[r] = (int)best;
#pragma unroll
            for (int p = 0; p < 4; ++p) if (pk[p] == best) pk[p] = 0u;
        }
    }
    __syncthreads();
    const int c = t >> 3, ch = t & 7;    // 8 lanes per candidate, 32 dims each
    if (c < nsel) {
        const int j = sel[c] & 8191;
        const float* fj = feats + (size_t)j * DIM + ch * 32;
        const float* fi = fi_s + ch * 32;
        double dd = 0.0, dot = 0.0;
#pragma unroll
        for (int q = 0; q < 8; ++q) {
            const float4 a4 = *reinterpret_cast<const float4*>(fi + q * 4);
            const float4 b4 = *reinterpret_cast<const float4*>(fj + q * 4);
            const double dx = (double)a4.x - b4.x, dy = (double)a4.y - b4.y;
            const double dz = (double)a4.z - b4.z, dw = (double)a4.w - b4.w;
            dd  += dx * dx + dy * dy + dz * dz + dw * dw;
            dot += (double)a4.x * b4.x + (double)a4.y * b4.y +
                   (double)a4.z * b4.z + (double)a4.w * b4.w;
        }
        dd  += __shfl_xor(dd, 1, 64);  dd  += __shfl_xor(dd, 2, 64);  dd  += __shfl_xor(dd, 4, 64);
        dot += __shfl_xor(dot, 1, 64); dot += __shfl_xor(dot, 2, 64); dot += __shfl_xor(dot, 4, 64);
        if (ch == 0) { kdd[c] = dd; kidx[c] = j; kdot[c] = (float)dot; }
    }
    __syncthreads();
    if (t < 64) {                        // wave 0: exact top-17 by (d2, idx)
        double kk = (t < nsel) ? kdd[t] : 1e300;
        int    jj = (t < nsel) ? kidx[t] : 0x7fffffff;
        float  ss = (t < nsel) ? kdot[t] : 0.f;
        for (int r = 0; r < NSLOT; ++r) {
            double bk = kk; int bj = jj; float bs = ss;
#pragma unroll
            for (int off = 1; off <= 32; off <<= 1) {
                const double ok = __shfl_xor(bk, off, 64);
                const int    oj = __shfl_xor(bj, off, 64);
                const float  os = __shfl_xor(bs, off, 64);
                if (ok < bk || (ok == bk && oj < bj)) { bk = ok; bj = oj; bs = os; }
            }
            if (t == 0) { fidx[(size_t)i * NSLOT + r] = bj; fscr[(size_t)i * NSLOT + r] = bs; }
            if (jj == bj) kk = 1e300;
        }
    }
}

// ---------------- K4: mutual mask + sparse softmax + mix + normalize ----------------
__global__ void fcm_out_kernel(const float* __restrict__ feats,
                               const int* __restrict__ knn_idx,
                               const float* __restrict__ knn_scr,
                               float* __restrict__ out) {
    const int w    = threadIdx.x >> 6;
    const int lane = threadIdx.x & 63;
    const int i    = blockIdx.x * 4 + w;

    int jt = -1; float st = 0.f; bool valid = false;
    if (lane < NSLOT) {
        jt = knn_idx[(size_t)i * NSLOT + lane];
        st = knn_scr[(size_t)i * NSLOT + lane];
        if (jt != i) {
            const int* nb = knn_idx + (size_t)jt * NSLOT;
#pragma unroll
            for (int s = 0; s < NSLOT; ++s) valid |= (nb[s] == i);
        }
    }
    float val = valid ? st : -INFINITY;
#pragma unroll
    for (int off = 32; off > 0; off >>= 1) val = fmaxf(val, __shfl_xor(val, off, 64));
    const float m  = fmaxf(1.0f, val);
    const float wt = valid ? expf(st - m) : 0.f;
    float ws = wt;
#pragma unroll
    for (int off = 32; off > 0; off >>= 1) ws += __shfl_xor(ws, off, 64);
    const float wdiag = expf(1.0f - m);
    const float inv   = 1.0f / (ws + wdiag);

    const float4 fi = *reinterpret_cast<const float4*>(feats + (size_t)i * DIM + lane * 4);
    float ax = fi.x * wdiag, ay = fi.y * wdiag, az = fi.z * wdiag, aw = fi.w * wdiag;
    for (int t = 0; t < NSLOT; ++t) {
        const float wtt = __shfl(wt, t, 64);
        const int   jj  = __shfl(jt, t, 64);
        if (wtt > 0.f) {
            const float4 fj = *reinterpret_cast<const float4*>(feats + (size_t)jj * DIM + lane * 4);
            ax = fmaf(wtt, fj.x, ax); ay = fmaf(wtt, fj.y, ay);
            az = fmaf(wtt, fj.z, az); aw = fmaf(wtt, fj.w, aw);
        }
    }
    const float ox = fmaf(ax, inv, fi.x), oy = fmaf(ay, inv, fi.y);
    const float oz = fmaf(az, inv, fi.z), ow = fmaf(aw, inv, fi.w);
    float nn = ox * ox + oy * oy + oz * oz + ow * ow;
#pragma unroll
    for (int off = 32; off > 0; off >>= 1) nn += __shfl_xor(nn, off, 64);
    const float scl = 1.0f / fmaxf(sqrtf(nn), 1e-12f);
    float4 o; o.x = ox * scl; o.y = oy * scl; o.z = oz * scl; o.w = ow * scl;
    *reinterpret_cast<float4*>(out + (size_t)i * DIM + lane * 4) = o;
}

extern "C" void kernel_launch(void* const* d_in, const int* in_sizes, int n_in,
                              void* d_out, int out_size, void* d_ws, size_t ws_size,
                              hipStream_t stream) {
    (void)in_sizes; (void)n_in; (void)out_size; (void)ws_size;
    const float* feats = (const float*)d_in[0];
    float* out = (float*)d_out;
    char* ws = (char*)d_ws;
    size_t off = 0;
    float*  sq    = (float*) (ws + off); off += NPTS * 4;                 // 32 KB
    float*  musig = (float*) (ws + off); off += 128;
    ushort* fb    = (ushort*)(ws + off); off += (size_t)NPTS * DIM * 2;   // 4 MB
    int*    cand  = (int*)   (ws + off); off += (size_t)NPTS * CAP * 4;   // 8 MB
    int*    cnt_g = (int*)   (ws + off); off += NPTS * 4;
    int*    fidx  = (int*)   (ws + off); off += NPTS * NSLOT * 4;
    float*  fscr  = (float*) (ws + off); off += NPTS * NSLOT * 4;

    prep_kernel<<<NPTS / 4, 256, 0, stream>>>(feats, fb, sq, cnt_g);
    stats_kernel<<<1, 1024, 0, stream>>>(sq, musig);
    gemm_select_kernel<<<(NPTS / 64) * 4, 512, 0, stream>>>(fb, sq, musig, cand, cnt_g);
    fallback_kernel<<<64, 256, 0, stream>>>(feats, sq, cand, cnt_g);
    refine_kernel<<<NPTS, 256, 0, stream>>>(feats, cand, cnt_g, fidx, fscr);
    fcm_out_kernel<<<NPTS / 4, 256, 0, stream>>>(feats, fidx, fscr, out);
}

// Round 11
// 204.699 us; speedup vs baseline: 1.5852x; 1.0744x over previous
//
#include <hip/hip_runtime.h>
#include <math.h>

// FCM mutual-kNN attention mixing. N=8192, D=256, K=16.
//   K1 prep:   feats->bf16, row sqnorms, zero cnt_g
//   K1b stats: deterministic reduction of sq -> mu/var
//   K2 gemm:   bf16 MFMA F F^T, 64 rows x 2048-col quarter, dbuf LDS staged via
//              global_load_lds (pre-swizzled source, linear dest), fused
//              threshold select -> packed (keyq<<13)|idx LDS cbuf -> merge.
//   K2b fallback: detect + full-rescan repair of bad rows (expected none)
//   K3 refine: one wave/row, fp64 exact d2+dot over <=256 cands -> exact top-17
//   K4 out:    mutual mask + sparse softmax + mix + normalize
#define NPTS 8192
#define DIM  256
#define NSLOT 17
#define CAP  256
#define LCAP 48
#define ZTH  (-2.45f)
typedef unsigned int uint;
typedef unsigned short ushort;
typedef __attribute__((ext_vector_type(8))) short bf16x8;
typedef __attribute__((ext_vector_type(4))) float f32x4;

__device__ __forceinline__ ushort f2bf(float f) {
    uint x = __float_as_uint(f);
    return (ushort)((x + 0x7fffu + ((x >> 16) & 1u)) >> 16);
}

// ---------------- K1: bf16 copy + sqnorms + cnt_g=0 ----------------
__global__ void prep_kernel(const float* __restrict__ feats, ushort* __restrict__ fb,
                            float* __restrict__ sq, int* __restrict__ cnt_g) {
    const int row  = blockIdx.x * 4 + (threadIdx.x >> 6);
    const int lane = threadIdx.x & 63;
    const float4 v = *reinterpret_cast<const float4*>(feats + (size_t)row * DIM + lane * 4);
    ushort4 b; b.x = f2bf(v.x); b.y = f2bf(v.y); b.z = f2bf(v.z); b.w = f2bf(v.w);
    *reinterpret_cast<ushort4*>(fb + (size_t)row * DIM + lane * 4) = b;
    float p = v.x * v.x + v.y * v.y + v.z * v.z + v.w * v.w;
#pragma unroll
    for (int off = 32; off > 0; off >>= 1) p += __shfl_down(p, off, 64);
    if (lane == 0) { sq[row] = p; cnt_g[row] = 0; }
}

// ---------------- K1b: deterministic stats (mu, var) ----------------
__global__ void stats_kernel(const float* __restrict__ sq, float* __restrict__ musig) {
    __shared__ double s0s[16], s1s[16];
    const int t = threadIdx.x, lane = t & 63, w = t >> 6;
    double s0 = 0.0, s1 = 0.0;
    for (int r = t; r < NPTS; r += 1024) {
        const double v = (double)sq[r];
        s0 += v; s1 += v * v;
    }
#pragma unroll
    for (int off = 32; off > 0; off >>= 1) {
        s0 += __shfl_down(s0, off, 64);
        s1 += __shfl_down(s1, off, 64);
    }
    if (lane == 0) { s0s[w] = s0; s1s[w] = s1; }
    __syncthreads();
    if (t == 0) {
        double a0 = 0.0, a1 = 0.0;
#pragma unroll
        for (int q = 0; q < 16; ++q) { a0 += s0s[q]; a1 += s1s[q]; }
        const double mu = a0 / NPTS;
        const double var = a1 / NPTS - mu * mu;
        musig[0] = (float)mu;
        musig[1] = (float)fmax(var, 1.0);
    }
}

// ---------------- K2: MFMA GEMM + fused threshold select ----------------
// 512 thr = 8 waves. Block: 64 rows x 2048-col quarter; quarter pinned per XCD.
// B staging: global_load_lds width-16, linear LDS dest, per-lane pre-swizzled
// global source so LDS layout equals byte = col*128 + (ks*16 ^ ((col&7)<<4)).
__global__ __launch_bounds__(512, 2) void gemm_select_kernel(
    const ushort* __restrict__ fb, const float* __restrict__ sq,
    const float* __restrict__ musig, int* __restrict__ cand, int* __restrict__ cnt_g) {
    __shared__ ushort Bs[2][256 * 64];   // 64 KB, [buf][col][k] swizzled
    __shared__ int    cbuf[64][LCAP];    // 12 KB packed (keyq<<13)|idx
    __shared__ float  Ts[64], sqi_s[64];
    __shared__ int    cnt[64];
    __shared__ int    base_s[64], n_s[64];

    const int tid = threadIdx.x;
    const int w   = tid >> 6;
    const int l   = tid & 63;
    const int l15 = l & 15, lg = l >> 4;
    const int h   = w >> 2;
    const int g   = w & 3;
    const int rowblk = (blockIdx.x >> 3) * 2 + (blockIdx.x & 1);
    const int row0   = rowblk * 64;
    const int Jbase  = ((blockIdx.x & 7) >> 1) * 2048;

    if (tid < 64) {
        const float mu  = musig[0];
        const float var = musig[1];
        const float qi  = sq[row0 + tid];
        sqi_s[tid] = qi;
        Ts[tid]    = qi + mu + ZTH * sqrtf(var + 4.f * qi);
        cnt[tid]   = 0;
    }

    // staging geometry: issue q = w*4+p covers LDS bytes [q*1024, q*1024+1024)
    // lane l: col = q*8 + (l>>3), content k-slot ks = (l&7) ^ ((l>>3)&7)
    const int scol_off = l >> 3;                 // 0..7
    const int sks      = (l & 7) ^ ((l >> 3) & 7);

    // A resident: a[mf][ks] = F[row0 + h*32 + mf*16 + l15][ks*32 + lg*8 .. +7]
    bf16x8 a[2][8];
#pragma unroll
    for (int mf = 0; mf < 2; ++mf) {
        const ushort* ap = fb + (size_t)(row0 + h * 32 + mf * 16 + l15) * DIM + lg * 8;
#pragma unroll
        for (int ks = 0; ks < 8; ++ks)
            a[mf][ks] = *reinterpret_cast<const bf16x8*>(ap + ks * 32);
    }

    {   // prologue: stage chunk 0 into Bs[0] (async DMA)
#pragma unroll
        for (int p = 0; p < 4; ++p) {
            const int q   = w * 4 + p;
            const int col = q * 8 + scol_off;
            const ushort* gp = fb + (size_t)(Jbase + col) * DIM + sks * 8;
            char* lp = reinterpret_cast<char*>(Bs[0]) + q * 1024;
            __builtin_amdgcn_global_load_lds(
                (const __attribute__((address_space(1))) void*)gp,
                (__attribute__((address_space(3))) void*)lp, 16, 0, 0);
        }
    }

    f32x4 acc[2][4];
#pragma unroll
    for (int mf = 0; mf < 2; ++mf)
#pragma unroll
        for (int cf = 0; cf < 4; ++cf) acc[mf][cf] = (f32x4){0.f, 0.f, 0.f, 0.f};

    for (int tile = 0; tile < 8; ++tile) {
#pragma unroll
        for (int kc4 = 0; kc4 < 4; ++kc4) {
            __syncthreads();             // Bs[kc4&1] DMA complete; other buffer free
            const int cnext = tile * 4 + kc4 + 1;
            if (cnext < 32) {            // issue async DMA for next chunk
                const int Jn  = Jbase + (cnext >> 2) * 256;
                const int kcn = ((kc4 + 1) & 3) * 64;
                char* Bn = reinterpret_cast<char*>(Bs[(kc4 + 1) & 1]);
#pragma unroll
                for (int p = 0; p < 4; ++p) {
                    const int q   = w * 4 + p;
                    const int col = q * 8 + scol_off;
                    const ushort* gp = fb + (size_t)(Jn + col) * DIM + kcn + sks * 8;
                    __builtin_amdgcn_global_load_lds(
                        (const __attribute__((address_space(1))) void*)gp,
                        (__attribute__((address_space(3))) void*)(Bn + q * 1024), 16, 0, 0);
                }
            }
            {   // compute chunk from Bs[kc4&1]
                const char* Bb = reinterpret_cast<const char*>(Bs[kc4 & 1]);
#pragma unroll
                for (int kk = 0; kk < 2; ++kk) {
                    bf16x8 b[4];
#pragma unroll
                    for (int cf = 0; cf < 4; ++cf) {
                        const int col = g * 64 + cf * 16 + l15;
                        b[cf] = *reinterpret_cast<const bf16x8*>(
                            Bb + col * 128 + ((kk * 64 + lg * 16) ^ ((col & 7) << 4)));
                    }
#pragma unroll
                    for (int mf = 0; mf < 2; ++mf)
#pragma unroll
                        for (int cf = 0; cf < 4; ++cf)
                            acc[mf][cf] = __builtin_amdgcn_mfma_f32_16x16x32_bf16(
                                a[mf][kc4 * 2 + kk], b[cf], acc[mf][cf], 0, 0, 0);
                }
            }
        }
        // ---- per-tile epilogue: threshold select, packed into LDS cbuf ----
        const int Jt = Jbase + tile * 256;
        float sqc[4];
#pragma unroll
        for (int cf = 0; cf < 4; ++cf) sqc[cf] = sq[Jt + g * 64 + cf * 16 + l15];
#pragma unroll
        for (int mf = 0; mf < 2; ++mf)
#pragma unroll
            for (int cf = 0; cf < 4; ++cf)
#pragma unroll
                for (int r = 0; r < 4; ++r) {
                    const int row = h * 32 + mf * 16 + lg * 4 + r;
                    const float tt = Ts[row];
                    const float key = sqi_s[row] + sqc[cf] - 2.f * acc[mf][cf][r];
                    if (key < tt) {
                        const int kq2 = min((int)((tt - key) * 4096.f), 524287);
                        const uint val = ((uint)max(kq2, 0) << 13) |
                                         (uint)(Jt + g * 64 + cf * 16 + l15);
                        const int pos = atomicAdd(&cnt[row], 1);
                        if (pos < LCAP) cbuf[row][pos] = (int)val;
                    }
                }
#pragma unroll
        for (int mf = 0; mf < 2; ++mf)
#pragma unroll
            for (int cf = 0; cf < 4; ++cf) acc[mf][cf] = (f32x4){0.f, 0.f, 0.f, 0.f};
    }
    __syncthreads();
    if (tid < 64) {
        const int local = cnt[tid];
        const int n = min(local, LCAP);
        const int add = (local > LCAP) ? (n + (1 << 20)) : n;   // poison on overflow
        base_s[tid] = atomicAdd(&cnt_g[row0 + tid], add);
        n_s[tid] = n;
    }
    __syncthreads();
    for (int s = tid; s < 64 * LCAP; s += 512) {
        const int r = s / LCAP, k2 = s - r * LCAP;
        if (k2 < n_s[r]) {
            const int b = base_s[r] + k2;
            if (b < CAP) cand[(size_t)(row0 + r) * CAP + b] = cbuf[r][k2];
        }
    }
}

// ---------------- K2b: detect + repair bad rows (expected none) ----------------
__global__ void fallback_kernel(const float* __restrict__ feats, const float* __restrict__ sq,
                                int* __restrict__ cand, int* __restrict__ cnt_g) {
    __shared__ float fi_s[DIM];
    __shared__ float keys[NPTS];
    __shared__ float rkey[4];
    __shared__ int   rid[4];
    const int t = threadIdx.x;
    for (int row = blockIdx.x; row < NPTS; row += gridDim.x) {
        const int v = cnt_g[row];
        if (v >= NSLOT && v <= CAP) continue;
        fi_s[t] = feats[(size_t)row * DIM + t];
        __syncthreads();
        const float sqi = sq[row];
        for (int p = 0; p < NPTS / 256; ++p) {
            const int jj = p * 256 + t;
            const float* fj = feats + (size_t)jj * DIM;
            float d = 0.f;
            for (int dq = 0; dq < DIM / 4; ++dq) {
                const float4 b4 = *reinterpret_cast<const float4*>(fj + dq * 4);
                const float4 a4 = *reinterpret_cast<const float4*>(&fi_s[dq * 4]);
                d = fmaf(a4.x, b4.x, fmaf(a4.y, b4.y, fmaf(a4.z, b4.z, fmaf(a4.w, b4.w, d))));
            }
            keys[jj] = sqi + sq[jj] - 2.f * d;
        }
        __syncthreads();
        for (int r = 0; r < 64; ++r) {
            float bk = INFINITY; int bj = 0x7fffffff;
            for (int p = 0; p < NPTS / 256; ++p) {
                const int jj = p * 256 + t;
                const float kv = keys[jj];
                if (kv < bk || (kv == bk && jj < bj)) { bk = kv; bj = jj; }
            }
#pragma unroll
            for (int off = 1; off <= 32; off <<= 1) {
                const float ok = __shfl_xor(bk, off, 64);
                const int   oj = __shfl_xor(bj, off, 64);
                if (ok < bk || (ok == bk && oj < bj)) { bk = ok; bj = oj; }
            }
            if ((t & 63) == 0) { rkey[t >> 6] = bk; rid[t >> 6] = bj; }
            __syncthreads();
            float fk = rkey[0]; int fj2 = rid[0];
#pragma unroll
            for (int q = 1; q < 4; ++q)
                if (rkey[q] < fk || (rkey[q] == fk && rid[q] < fj2)) { fk = rkey[q]; fj2 = rid[q]; }
            if (t == 0) {   // rank-ordered packed key (idx in low 13 bits)
                cand[(size_t)row * CAP + r] = (int)(((uint)(524287 - r) << 13) | (uint)fj2);
                keys[fj2] = INFINITY;
            }
            __syncthreads();
        }
        if (t == 0) cnt_g[row] = 64;
        __syncthreads();
    }
}

// ---------------- K3: fp64 refine, one wave per row -> exact top-17 ----------------
// 4 rows/block (one per wave); <=4 cands/lane, statically unrolled; selection is
// a wave-private 17-round butterfly. fi_s reads are broadcast (conflict-free).
__global__ __launch_bounds__(256) void refine_kernel(
    const float* __restrict__ feats, const int* __restrict__ cand,
    const int* __restrict__ cnt_g, int* __restrict__ fidx, float* __restrict__ fscr) {
    __shared__ float fi_s[4][DIM];
    const int w = threadIdx.x >> 6, l = threadIdx.x & 63;
    const int i = blockIdx.x * 4 + w;
    *reinterpret_cast<float4*>(&fi_s[w][l * 4]) =
        *reinterpret_cast<const float4*>(feats + (size_t)i * DIM + l * 4);
    __syncthreads();                     // the only barrier; waves diverge after
    const int nc = min(cnt_g[i], CAP);
    double kdd[4]; int kj[4]; float kdot[4];
#pragma unroll
    for (int p = 0; p < 4; ++p) { kdd[p] = 1e300; kj[p] = 0x7fffffff; kdot[p] = 0.f; }
#pragma unroll
    for (int p = 0; p < 4; ++p) {
        const int c = p * 64 + l;
        if (c < nc) {
            const int j = cand[(size_t)i * CAP + c] & 8191;
            const float* fj = feats + (size_t)j * DIM;
            double dd = 0.0, dot = 0.0;
#pragma unroll 8
            for (int d = 0; d < DIM; d += 4) {
                const float4 b4 = *reinterpret_cast<const float4*>(fj + d);
                const float4 a4 = *reinterpret_cast<const float4*>(&fi_s[w][d]);
                const double dx = (double)a4.x - b4.x, dy = (double)a4.y - b4.y;
                const double dz = (double)a4.z - b4.z, dw2 = (double)a4.w - b4.w;
                dd  += dx * dx + dy * dy + dz * dz + dw2 * dw2;
                dot += (double)a4.x * b4.x + (double)a4.y * b4.y +
                       (double)a4.z * b4.z + (double)a4.w * b4.w;
            }
            kdd[p] = dd; kj[p] = j; kdot[p] = (float)dot;
        }
    }
    for (int r = 0; r < NSLOT; ++r) {
        double bk = kdd[0]; int bj = kj[0]; float bs = kdot[0];
#pragma unroll
        for (int p = 1; p < 4; ++p)
            if (kdd[p] < bk || (kdd[p] == bk && kj[p] < bj)) { bk = kdd[p]; bj = kj[p]; bs = kdot[p]; }
#pragma unroll
        for (int off = 1; off <= 32; off <<= 1) {
            const double ok = __shfl_xor(bk, off, 64);
            const int    oj = __shfl_xor(bj, off, 64);
            const float  os = __shfl_xor(bs, off, 64);
            if (ok < bk || (ok == bk && oj < bj)) { bk = ok; bj = oj; bs = os; }
        }
        if (l == 0) { fidx[(size_t)i * NSLOT + r] = bj; fscr[(size_t)i * NSLOT + r] = bs; }
#pragma unroll
        for (int p = 0; p < 4; ++p) if (kj[p] == bj) kdd[p] = 1e300;
    }
}

// ---------------- K4: mutual mask + sparse softmax + mix + normalize ----------------
__global__ void fcm_out_kernel(const float* __restrict__ feats,
                               const int* __restrict__ knn_idx,
                               const float* __restrict__ knn_scr,
                               float* __restrict__ out) {
    const int w    = threadIdx.x >> 6;
    const int lane = threadIdx.x & 63;
    const int i    = blockIdx.x * 4 + w;

    int jt = -1; float st = 0.f; bool valid = false;
    if (lane < NSLOT) {
        jt = knn_idx[(size_t)i * NSLOT + lane];
        st = knn_scr[(size_t)i * NSLOT + lane];
        if (jt != i) {
            const int* nb = knn_idx + (size_t)jt * NSLOT;
#pragma unroll
            for (int s = 0; s < NSLOT; ++s) valid |= (nb[s] == i);
        }
    }
    float val = valid ? st : -INFINITY;
#pragma unroll
    for (int off = 32; off > 0; off >>= 1) val = fmaxf(val, __shfl_xor(val, off, 64));
    const float m  = fmaxf(1.0f, val);
    const float wt = valid ? expf(st - m) : 0.f;
    float ws = wt;
#pragma unroll
    for (int off = 32; off > 0; off >>= 1) ws += __shfl_xor(ws, off, 64);
    const float wdiag = expf(1.0f - m);
    const float inv   = 1.0f / (ws + wdiag);

    const float4 fi = *reinterpret_cast<const float4*>(feats + (size_t)i * DIM + lane * 4);
    float ax = fi.x * wdiag, ay = fi.y * wdiag, az = fi.z * wdiag, aw = fi.w * wdiag;
    for (int t = 0; t < NSLOT; ++t) {
        const float wtt = __shfl(wt, t, 64);
        const int   jj  = __shfl(jt, t, 64);
        if (wtt > 0.f) {
            const float4 fj = *reinterpret_cast<const float4*>(feats + (size_t)jj * DIM + lane * 4);
            ax = fmaf(wtt, fj.x, ax); ay = fmaf(wtt, fj.y, ay);
            az = fmaf(wtt, fj.z, az); aw = fmaf(wtt, fj.w, aw);
        }
    }
    const float ox = fmaf(ax, inv, fi.x), oy = fmaf(ay, inv, fi.y);
    const float oz = fmaf(az, inv, fi.z), ow = fmaf(aw, inv, fi.w);
    float nn = ox * ox + oy * oy + oz * oz + ow * ow;
#pragma unroll
    for (int off = 32; off > 0; off >>= 1) nn += __shfl_xor(nn, off, 64);
    const float scl = 1.0f / fmaxf(sqrtf(nn), 1e-12f);
    float4 o; o.x = ox * scl; o.y = oy * scl; o.z = oz * scl; o.w = ow * scl;
    *reinterpret_cast<float4*>(out + (size_t)i * DIM + lane * 4) = o;
}

extern "C" void kernel_launch(void* const* d_in, const int* in_sizes, int n_in,
                              void* d_out, int out_size, void* d_ws, size_t ws_size,
                              hipStream_t stream) {
    (void)in_sizes; (void)n_in; (void)out_size; (void)ws_size;
    const float* feats = (const float*)d_in[0];
    float* out = (float*)d_out;
    char* ws = (char*)d_ws;
    size_t off = 0;
    float*  sq    = (float*) (ws + off); off += NPTS * 4;                 // 32 KB
    float*  musig = (float*) (ws + off); off += 128;
    ushort* fb    = (ushort*)(ws + off); off += (size_t)NPTS * DIM * 2;   // 4 MB
    int*    cand  = (int*)   (ws + off); off += (size_t)NPTS * CAP * 4;   // 8 MB
    int*    cnt_g = (int*)   (ws + off); off += NPTS * 4;
    int*    fidx  = (int*)   (ws + off); off += NPTS * NSLOT * 4;
    float*  fscr  = (float*) (ws + off); off += NPTS * NSLOT * 4;

    prep_kernel<<<NPTS / 4, 256, 0, stream>>>(feats, fb, sq, cnt_g);
    stats_kernel<<<1, 1024, 0, stream>>>(sq, musig);
    gemm_select_kernel<<<(NPTS / 64) * 4, 512, 0, stream>>>(fb, sq, musig, cand, cnt_g);
    fallback_kernel<<<64, 256, 0, stream>>>(feats, sq, cand, cnt_g);
    refine_kernel<<<NPTS / 4, 256, 0, stream>>>(feats, cand, cnt_g, fidx, fscr);
    fcm_out_kernel<<<NPTS / 4, 256, 0, stream>>>(feats, fidx, fscr, out);
}

// Round 12
// 194.442 us; speedup vs baseline: 1.6688x; 1.0527x over previous
//
#include <hip/hip_runtime.h>
#include <math.h>

// FCM mutual-kNN attention mixing. N=8192, D=256, K=16.
//   K1 prep:   feats->bf16, row sqnorms, zero cnt_g
//   K1b stats: deterministic reduction of sq -> mu/var
//   K2 gemm:   A panel (64x256) in LDS (XOR swizzle), B streamed global->regs,
//              ZERO barriers in main loop; fused threshold select -> packed
//              (keyq<<13)|idx LDS cbuf -> one merge/block. launch_bounds(512,2).
//   K2b fallback: detect + full-rescan repair of bad rows (expected none)
//   K3 refine: one wave/row, fp64 exact d2+dot over <=256 cands -> exact top-17
//   K4 out:    mutual mask + sparse softmax + mix + normalize
#define NPTS 8192
#define DIM  256
#define NSLOT 17
#define CAP  256
#define LCAP 48
#define ZTH  (-2.45f)
typedef unsigned int uint;
typedef unsigned short ushort;
typedef __attribute__((ext_vector_type(8))) short bf16x8;
typedef __attribute__((ext_vector_type(4))) float f32x4;

__device__ __forceinline__ ushort f2bf(float f) {
    uint x = __float_as_uint(f);
    return (ushort)((x + 0x7fffu + ((x >> 16) & 1u)) >> 16);
}

// ---------------- K1: bf16 copy + sqnorms + cnt_g=0 ----------------
__global__ void prep_kernel(const float* __restrict__ feats, ushort* __restrict__ fb,
                            float* __restrict__ sq, int* __restrict__ cnt_g) {
    const int row  = blockIdx.x * 4 + (threadIdx.x >> 6);
    const int lane = threadIdx.x & 63;
    const float4 v = *reinterpret_cast<const float4*>(feats + (size_t)row * DIM + lane * 4);
    ushort4 b; b.x = f2bf(v.x); b.y = f2bf(v.y); b.z = f2bf(v.z); b.w = f2bf(v.w);
    *reinterpret_cast<ushort4*>(fb + (size_t)row * DIM + lane * 4) = b;
    float p = v.x * v.x + v.y * v.y + v.z * v.z + v.w * v.w;
#pragma unroll
    for (int off = 32; off > 0; off >>= 1) p += __shfl_down(p, off, 64);
    if (lane == 0) { sq[row] = p; cnt_g[row] = 0; }
}

// ---------------- K1b: deterministic stats (mu, var) ----------------
__global__ void stats_kernel(const float* __restrict__ sq, float* __restrict__ musig) {
    __shared__ double s0s[16], s1s[16];
    const int t = threadIdx.x, lane = t & 63, w = t >> 6;
    double s0 = 0.0, s1 = 0.0;
    for (int r = t; r < NPTS; r += 1024) {
        const double v = (double)sq[r];
        s0 += v; s1 += v * v;
    }
#pragma unroll
    for (int off = 32; off > 0; off >>= 1) {
        s0 += __shfl_down(s0, off, 64);
        s1 += __shfl_down(s1, off, 64);
    }
    if (lane == 0) { s0s[w] = s0; s1s[w] = s1; }
    __syncthreads();
    if (t == 0) {
        double a0 = 0.0, a1 = 0.0;
#pragma unroll
        for (int q = 0; q < 16; ++q) { a0 += s0s[q]; a1 += s1s[q]; }
        const double mu = a0 / NPTS;
        const double var = a1 / NPTS - mu * mu;
        musig[0] = (float)mu;
        musig[1] = (float)fmax(var, 1.0);
    }
}

// ---------------- K2: barrier-free MFMA GEMM + fused threshold select ----------------
// 512 thr = 8 waves. Block: 64 rows x 2048-col quarter (quarter pinned per XCD).
// Wave w owns cols w*32..w*32+31 of each 256-col tile -> B in registers, no
// cross-wave sharing, no main-loop barriers. A panel in LDS, 2-way-free swizzle.
__global__ __launch_bounds__(512, 2) void gemm_select_kernel(
    const ushort* __restrict__ fb, const float* __restrict__ sq,
    const float* __restrict__ musig, int* __restrict__ cand, int* __restrict__ cnt_g) {
    __shared__ ushort As[64 * 256];      // 32 KB [row][k], byte ^= (row&7)<<4
    __shared__ int    cbuf[64][LCAP];    // 12 KB packed (keyq<<13)|idx
    __shared__ float  Ts[64], sqi_s[64];
    __shared__ int    cnt[64];
    __shared__ int    base_s[64], n_s[64];

    const int tid = threadIdx.x;
    const int w   = tid >> 6;
    const int l   = tid & 63;
    const int l15 = l & 15, lg = l >> 4;
    const int rowblk = (blockIdx.x >> 3) * 2 + (blockIdx.x & 1);
    const int row0   = rowblk * 64;
    const int Jbase  = ((blockIdx.x & 7) >> 1) * 2048;

    if (tid < 64) {
        const float mu  = musig[0];
        const float var = musig[1];
        const float qi  = sq[row0 + tid];
        sqi_s[tid] = qi;
        Ts[tid]    = qi + mu + ZTH * sqrtf(var + 4.f * qi);
        cnt[tid]   = 0;
    }
    {   // stage A panel once: 64 rows x 256 k
        const int row = tid >> 3, kq = tid & 7;
        const ushort* src = fb + (size_t)(row0 + row) * DIM;
        char* dst = reinterpret_cast<char*>(As);
        const int sw = (row & 7) << 4;
#pragma unroll
        for (int p = 0; p < 4; ++p) {
            const bf16x8 v = *reinterpret_cast<const bf16x8*>(src + (kq + p * 8) * 8);
            *reinterpret_cast<bf16x8*>(dst + ((row * 512 + (kq + p * 8) * 16) ^ sw)) = v;
        }
    }
    __syncthreads();                     // the ONLY barrier before the merge

    const int gcol = w * 32;
    const ushort* colp = fb + (size_t)(Jbase + gcol + l15) * DIM + lg * 8;

    bf16x8 bb[2][2];
#pragma unroll
    for (int cf = 0; cf < 2; ++cf)
        bb[0][cf] = *reinterpret_cast<const bf16x8*>(colp + cf * 16 * DIM);

    for (int tile = 0; tile < 8; ++tile) {
        f32x4 acc[4][2];
#pragma unroll
        for (int mf = 0; mf < 4; ++mf) {
            acc[mf][0] = (f32x4){0.f, 0.f, 0.f, 0.f};
            acc[mf][1] = (f32x4){0.f, 0.f, 0.f, 0.f};
        }
#pragma unroll
        for (int ks = 0; ks < 8; ++ks) {
            const int cur = ks & 1;
            // prefetch next 32-k step (register ping-pong, no barrier)
            if (tile < 7 || ks < 7) {
                const int ntile = (ks == 7) ? tile + 1 : tile;
                const int nks   = (ks == 7) ? 0 : ks + 1;
#pragma unroll
                for (int cf = 0; cf < 2; ++cf)
                    bb[cur ^ 1][cf] = *reinterpret_cast<const bf16x8*>(
                        colp + (ntile * 256 + cf * 16) * DIM + nks * 32);
            }
            bf16x8 af[4];
#pragma unroll
            for (int mf = 0; mf < 4; ++mf) {
                const int row = mf * 16 + l15;
                af[mf] = *reinterpret_cast<const bf16x8*>(
                    reinterpret_cast<const char*>(As) +
                    ((row * 512 + ks * 64 + lg * 16) ^ ((row & 7) << 4)));
            }
#pragma unroll
            for (int mf = 0; mf < 4; ++mf) {
                acc[mf][0] = __builtin_amdgcn_mfma_f32_16x16x32_bf16(af[mf], bb[cur][0], acc[mf][0], 0, 0, 0);
                acc[mf][1] = __builtin_amdgcn_mfma_f32_16x16x32_bf16(af[mf], bb[cur][1], acc[mf][1], 0, 0, 0);
            }
        }
        // ---- per-tile epilogue: threshold select, packed into LDS cbuf ----
        const int Jt = Jbase + tile * 256;
        float sqc[2];
#pragma unroll
        for (int cf = 0; cf < 2; ++cf) sqc[cf] = sq[Jt + gcol + cf * 16 + l15];
#pragma unroll
        for (int mf = 0; mf < 4; ++mf)
#pragma unroll
            for (int cf = 0; cf < 2; ++cf)
#pragma unroll
                for (int r = 0; r < 4; ++r) {
                    const int row = mf * 16 + lg * 4 + r;
                    const float tt = Ts[row];
                    const float key = sqi_s[row] + sqc[cf] - 2.f * acc[mf][cf][r];
                    if (key < tt) {
                        const int kq2 = min((int)((tt - key) * 4096.f), 524287);
                        const uint val = ((uint)max(kq2, 0) << 13) |
                                         (uint)(Jt + gcol + cf * 16 + l15);
                        const int pos = atomicAdd(&cnt[row], 1);
                        if (pos < LCAP) cbuf[row][pos] = (int)val;
                    }
                }
    }
    __syncthreads();
    if (tid < 64) {
        const int local = cnt[tid];
        const int n = min(local, LCAP);
        const int add = (local > LCAP) ? (n + (1 << 20)) : n;   // poison on overflow
        base_s[tid] = atomicAdd(&cnt_g[row0 + tid], add);
        n_s[tid] = n;
    }
    __syncthreads();
    for (int s = tid; s < 64 * LCAP; s += 512) {
        const int r = s / LCAP, k2 = s - r * LCAP;
        if (k2 < n_s[r]) {
            const int b = base_s[r] + k2;
            if (b < CAP) cand[(size_t)(row0 + r) * CAP + b] = cbuf[r][k2];
        }
    }
}

// ---------------- K2b: detect + repair bad rows (expected none) ----------------
__global__ void fallback_kernel(const float* __restrict__ feats, const float* __restrict__ sq,
                                int* __restrict__ cand, int* __restrict__ cnt_g) {
    __shared__ float fi_s[DIM];
    __shared__ float keys[NPTS];
    __shared__ float rkey[4];
    __shared__ int   rid[4];
    const int t = threadIdx.x;
    for (int row = blockIdx.x; row < NPTS; row += gridDim.x) {
        const int v = cnt_g[row];
        if (v >= NSLOT && v <= CAP) continue;
        fi_s[t] = feats[(size_t)row * DIM + t];
        __syncthreads();
        const float sqi = sq[row];
        for (int p = 0; p < NPTS / 256; ++p) {
            const int jj = p * 256 + t;
            const float* fj = feats + (size_t)jj * DIM;
            float d = 0.f;
            for (int dq = 0; dq < DIM / 4; ++dq) {
                const float4 b4 = *reinterpret_cast<const float4*>(fj + dq * 4);
                const float4 a4 = *reinterpret_cast<const float4*>(&fi_s[dq * 4]);
                d = fmaf(a4.x, b4.x, fmaf(a4.y, b4.y, fmaf(a4.z, b4.z, fmaf(a4.w, b4.w, d))));
            }
            keys[jj] = sqi + sq[jj] - 2.f * d;
        }
        __syncthreads();
        for (int r = 0; r < 64; ++r) {
            float bk = INFINITY; int bj = 0x7fffffff;
            for (int p = 0; p < NPTS / 256; ++p) {
                const int jj = p * 256 + t;
                const float kv = keys[jj];
                if (kv < bk || (kv == bk && jj < bj)) { bk = kv; bj = jj; }
            }
#pragma unroll
            for (int off = 1; off <= 32; off <<= 1) {
                const float ok = __shfl_xor(bk, off, 64);
                const int   oj = __shfl_xor(bj, off, 64);
                if (ok < bk || (ok == bk && oj < bj)) { bk = ok; bj = oj; }
            }
            if ((t & 63) == 0) { rkey[t >> 6] = bk; rid[t >> 6] = bj; }
            __syncthreads();
            float fk = rkey[0]; int fj2 = rid[0];
#pragma unroll
            for (int q = 1; q < 4; ++q)
                if (rkey[q] < fk || (rkey[q] == fk && rid[q] < fj2)) { fk = rkey[q]; fj2 = rid[q]; }
            if (t == 0) {   // rank-ordered packed key (idx in low 13 bits)
                cand[(size_t)row * CAP + r] = (int)(((uint)(524287 - r) << 13) | (uint)fj2);
                keys[fj2] = INFINITY;
            }
            __syncthreads();
        }
        if (t == 0) cnt_g[row] = 64;
        __syncthreads();
    }
}

// ---------------- K3: fp64 refine, one wave per row -> exact top-17 ----------------
__global__ __launch_bounds__(256) void refine_kernel(
    const float* __restrict__ feats, const int* __restrict__ cand,
    const int* __restrict__ cnt_g, int* __restrict__ fidx, float* __restrict__ fscr) {
    __shared__ float fi_s[4][DIM];
    const int w = threadIdx.x >> 6, l = threadIdx.x & 63;
    const int i = blockIdx.x * 4 + w;
    *reinterpret_cast<float4*>(&fi_s[w][l * 4]) =
        *reinterpret_cast<const float4*>(feats + (size_t)i * DIM + l * 4);
    __syncthreads();                     // the only barrier; waves diverge after
    const int nc = min(cnt_g[i], CAP);
    double kdd[4]; int kj[4]; float kdot[4];
#pragma unroll
    for (int p = 0; p < 4; ++p) { kdd[p] = 1e300; kj[p] = 0x7fffffff; kdot[p] = 0.f; }
#pragma unroll
    for (int p = 0; p < 4; ++p) {
        const int c = p * 64 + l;
        if (c < nc) {
            const int j = cand[(size_t)i * CAP + c] & 8191;
            const float* fj = feats + (size_t)j * DIM;
            double dd = 0.0, dot = 0.0;
#pragma unroll 8
            for (int d = 0; d < DIM; d += 4) {
                const float4 b4 = *reinterpret_cast<const float4*>(fj + d);
                const float4 a4 = *reinterpret_cast<const float4*>(&fi_s[w][d]);
                const double dx = (double)a4.x - b4.x, dy = (double)a4.y - b4.y;
                const double dz = (double)a4.z - b4.z, dw2 = (double)a4.w - b4.w;
                dd  += dx * dx + dy * dy + dz * dz + dw2 * dw2;
                dot += (double)a4.x * b4.x + (double)a4.y * b4.y +
                       (double)a4.z * b4.z + (double)a4.w * b4.w;
            }
            kdd[p] = dd; kj[p] = j; kdot[p] = (float)dot;
        }
    }
    for (int r = 0; r < NSLOT; ++r) {
        double bk = kdd[0]; int bj = kj[0]; float bs = kdot[0];
#pragma unroll
        for (int p = 1; p < 4; ++p)
            if (kdd[p] < bk || (kdd[p] == bk && kj[p] < bj)) { bk = kdd[p]; bj = kj[p]; bs = kdot[p]; }
#pragma unroll
        for (int off = 1; off <= 32; off <<= 1) {
            const double ok = __shfl_xor(bk, off, 64);
            const int    oj = __shfl_xor(bj, off, 64);
            const float  os = __shfl_xor(bs, off, 64);
            if (ok < bk || (ok == bk && oj < bj)) { bk = ok; bj = oj; bs = os; }
        }
        if (l == 0) { fidx[(size_t)i * NSLOT + r] = bj; fscr[(size_t)i * NSLOT + r] = bs; }
#pragma unroll
        for (int p = 0; p < 4; ++p) if (kj[p] == bj) kdd[p] = 1e300;
    }
}

// ---------------- K4: mutual mask + sparse softmax + mix + normalize ----------------
__global__ void fcm_out_kernel(const float* __restrict__ feats,
                               const int* __restrict__ knn_idx,
                               const float* __restrict__ knn_scr,
                               float* __restrict__ out) {
    const int w    = threadIdx.x >> 6;
    const int lane = threadIdx.x & 63;
    const int i    = blockIdx.x * 4 + w;

    int jt = -1; float st = 0.f; bool valid = false;
    if (lane < NSLOT) {
        jt = knn_idx[(size_t)i * NSLOT + lane];
        st = knn_scr[(size_t)i * NSLOT + lane];
        if (jt != i) {
            const int* nb = knn_idx + (size_t)jt * NSLOT;
#pragma unroll
            for (int s = 0; s < NSLOT; ++s) valid |= (nb[s] == i);
        }
    }
    float val = valid ? st : -INFINITY;
#pragma unroll
    for (int off = 32; off > 0; off >>= 1) val = fmaxf(val, __shfl_xor(val, off, 64));
    const float m  = fmaxf(1.0f, val);
    const float wt = valid ? expf(st - m) : 0.f;
    float ws = wt;
#pragma unroll
    for (int off = 32; off > 0; off >>= 1) ws += __shfl_xor(ws, off, 64);
    const float wdiag = expf(1.0f - m);
    const float inv   = 1.0f / (ws + wdiag);

    const float4 fi = *reinterpret_cast<const float4*>(feats + (size_t)i * DIM + lane * 4);
    float ax = fi.x * wdiag, ay = fi.y * wdiag, az = fi.z * wdiag, aw = fi.w * wdiag;
    for (int t = 0; t < NSLOT; ++t) {
        const float wtt = __shfl(wt, t, 64);
        const int   jj  = __shfl(jt, t, 64);
        if (wtt > 0.f) {
            const float4 fj = *reinterpret_cast<const float4*>(feats + (size_t)jj * DIM + lane * 4);
            ax = fmaf(wtt, fj.x, ax); ay = fmaf(wtt, fj.y, ay);
            az = fmaf(wtt, fj.z, az); aw = fmaf(wtt, fj.w, aw);
        }
    }
    const float ox = fmaf(ax, inv, fi.x), oy = fmaf(ay, inv, fi.y);
    const float oz = fmaf(az, inv, fi.z), ow = fmaf(aw, inv, fi.w);
    float nn = ox * ox + oy * oy + oz * oz + ow * ow;
#pragma unroll
    for (int off = 32; off > 0; off >>= 1) nn += __shfl_xor(nn, off, 64);
    const float scl = 1.0f / fmaxf(sqrtf(nn), 1e-12f);
    float4 o; o.x = ox * scl; o.y = oy * scl; o.z = oz * scl; o.w = ow * scl;
    *reinterpret_cast<float4*>(out + (size_t)i * DIM + lane * 4) = o;
}

extern "C" void kernel_launch(void* const* d_in, const int* in_sizes, int n_in,
                              void* d_out, int out_size, void* d_ws, size_t ws_size,
                              hipStream_t stream) {
    (void)in_sizes; (void)n_in; (void)out_size; (void)ws_size;
    const float* feats = (const float*)d_in[0];
    float* out = (float*)d_out;
    char* ws = (char*)d_ws;
    size_t off = 0;
    float*  sq    = (float*) (ws + off); off += NPTS * 4;                 // 32 KB
    float*  musig = (float*) (ws + off); off += 128;
    ushort* fb    = (ushort*)(ws + off); off += (size_t)NPTS * DIM * 2;   // 4 MB
    int*    cand  = (int*)   (ws + off); off += (size_t)NPTS * CAP * 4;   // 8 MB
    int*    cnt_g = (int*)   (ws + off); off += NPTS * 4;
    int*    fidx  = (int*)   (ws + off); off += NPTS * NSLOT * 4;
    float*  fscr  = (float*) (ws + off); off += NPTS * NSLOT * 4;

    prep_kernel<<<NPTS / 4, 256, 0, stream>>>(feats, fb, sq, cnt_g);
    stats_kernel<<<1, 1024, 0, stream>>>(sq, musig);
    gemm_select_kernel<<<(NPTS / 64) * 4, 512, 0, stream>>>(fb, sq, musig, cand, cnt_g);
    fallback_kernel<<<64, 256, 0, stream>>>(feats, sq, cand, cnt_g);
    refine_kernel<<<NPTS / 4, 256, 0, stream>>>(feats, cand, cnt_g, fidx, fscr);
    fcm_out_kernel<<<NPTS / 4, 256, 0, stream>>>(feats, fidx, fscr, out);
}